// Round 17
// baseline (394.559 us; speedup 1.0000x reference)
//
#include <hip/hip_runtime.h>

#define NPIX 9216
#define NL   21
#define WW   96
#define RAD  16
#define NC   462            // monomials deg<=6 in 5 vars
#define NCP  480            // padded to 15 x 32
#define SK   8              // K-splits of GEMM1
#define KC   1152           // NPIX / SK
#define KW   288            // KC / 4 waves
#define L2E  1.44269504088896340736f

typedef __bf16 bf16x8 __attribute__((ext_vector_type(8)));
typedef float  f32x16 __attribute__((ext_vector_type(16)));

__device__ __forceinline__ float fexp2(float x) { return __builtin_amdgcn_exp2f(x); }

// ---------- prep: lifted Taylor features (both layouts) + spatial norm + QhT const rows ----------
// phi_a(f) = f^a / sqrt(a!), deg<=6; Phw[c][j] = phi_c(fj) e^{-sj} (c-major),
// Phi[i][c] = same values row-major. kernel(i,j) ~= sum_c Phw[c,i]*Phw[c,j] (deg-6 Taylor of e^u).
__global__ __launch_bounds__(256) void featK(const float* __restrict__ img,
                                             __bf16* __restrict__ Phw, __bf16* __restrict__ Phi,
                                             float* __restrict__ norm_s, __bf16* __restrict__ QhT) {
    int i = blockIdx.x * 256 + threadIdx.x;
    if (i >= NPIX) return;
    int y = i / WW, x = i - y * WW;
    float f0 = (float)x * (1.0f / 160.0f);
    float f1 = (float)y * (1.0f / 160.0f);
    float f2 = img[0 * NPIX + i] * (1.0f / 3.0f);
    float f3 = img[1 * NPIX + i] * (1.0f / 3.0f);
    float f4 = img[2 * NPIX + i] * (1.0f / 3.0f);
    float sn = 0.5f * (f0*f0 + f1*f1 + f2*f2 + f3*f3 + f4*f4);   // natural log space
    float wgt = fexp2(-sn * L2E);                                // e^{-s}
    QhT[(size_t)21 * NPIX + i] = (__bf16)1.0f;
    #pragma unroll
    for (int l = 22; l < 32; l++) QhT[(size_t)l * NPIX + i] = (__bf16)0.0f;
    // monomial emission (same order everywhere); Phi buffered 8-wide for 16B stores
    const float rf[7] = {1.f, 1.f, 0.5f, 1.f/6.f, 1.f/24.f, 1.f/120.f, 1.f/720.f};
    __bf16 buf[8];
    int c = 0;
    float p0 = 1.f;
    for (int a0 = 0; a0 <= 6; a0++) {
        float p1 = p0;
        for (int a1 = 0; a1 <= 6 - a0; a1++) {
            float p2 = p1;
            for (int a2 = 0; a2 <= 6 - a0 - a1; a2++) {
                float p3 = p2;
                for (int a3 = 0; a3 <= 6 - a0 - a1 - a2; a3++) {
                    float p4 = p3;
                    for (int a4 = 0; a4 <= 6 - a0 - a1 - a2 - a3; a4++) {
                        float v = p4 * sqrtf(rf[a0] * rf[a1] * rf[a2] * rf[a3] * rf[a4]) * wgt;
                        __bf16 h = (__bf16)v;
                        Phw[(size_t)c * NPIX + i] = h;      // coalesced (lockstep c)
                        buf[c & 7] = h;
                        if ((c & 7) == 7)
                            *reinterpret_cast<bf16x8*>(Phi + (size_t)i * NCP + (c & ~7)) =
                                *reinterpret_cast<bf16x8*>(buf);
                        c++;
                        p4 *= f4;
                    }
                    p3 *= f3;
                }
                p2 *= f2;
            }
            p1 *= f1;
        }
        p0 *= f0;
    }
    for (; c < NCP; c++) {                                   // pad 462..479 with zeros
        Phw[(size_t)c * NPIX + i] = (__bf16)0.0f;
        buf[c & 7] = (__bf16)0.0f;
        if ((c & 7) == 7)
            *reinterpret_cast<bf16x8*>(Phi + (size_t)i * NCP + (c & ~7)) =
                *reinterpret_cast<bf16x8*>(buf);
    }
    // truncated separable spatial norm (unchanged)
    const float cs = (-0.5f / 9.0f) * L2E;
    float sx = 0.f, sy = 0.f;
    int xa = max(0, x - RAD), xb = min(WW - 1, x + RAD);
    int ya = max(0, y - RAD), yb = min(WW - 1, y + RAD);
    for (int t = xa; t <= xb; t++) { float dx = (float)(x - t); sx += fexp2(cs * dx * dx); }
    for (int t = ya; t <= yb; t++) { float dy = (float)(y - t); sy += fexp2(cs * dy * dy); }
    norm_s[i] = 1.0f / (sx * sy + 1e-8f);
}

// ---------- fold 21x21 matrices ----------
__global__ __launch_bounds__(448) void matK(const float* __restrict__ Cm, const float* __restrict__ Wsm,
                                            const float* __restrict__ Wbm,
                                            float* __restrict__ Ms, float* __restrict__ Mb) {
    int t = threadIdx.x;
    if (t >= NL * NL) return;
    int l = t / NL, p = t - l * NL;
    float a = 0.f, b = 0.f;
    for (int m = 0; m < NL; m++) {
        float c = Cm[l * NL + m];
        a = fmaf(c, Wsm[m * NL + p], a);
        b = fmaf(c, Wbm[m * NL + p], b);
    }
    Ms[t] = a; Mb[t] = b;
}

// ---------- iter-0 softmax -> QhT ----------
__global__ __launch_bounds__(256) void smax0(const float* __restrict__ cur, __bf16* __restrict__ QhT) {
    int i = blockIdx.x * 256 + threadIdx.x;
    if (i >= NPIX) return;
    float v[NL]; float m = -1e30f;
    #pragma unroll
    for (int l = 0; l < NL; l++) { v[l] = cur[l * NPIX + i]; m = fmaxf(m, v[l]); }
    float s = 0.f;
    #pragma unroll
    for (int l = 0; l < NL; l++) { v[l] = fexp2((v[l] - m) * L2E); s += v[l]; }
    float inv = 1.0f / s;
    #pragma unroll
    for (int l = 0; l < NL; l++) QhT[(size_t)l * NPIX + i] = (__bf16)(v[l] * inv);
}

// ---------- D1: GEMM1 partials (blocks 0..119) | spatX (blocks 120..875) ----------
// g1: PRT[sk][l][c] = sum_{j in chunk sk} Phw[c,j] * QhT[l,j]  (per-block 4-wave split-K + LDS reduce)
__global__ __launch_bounds__(256) void fusedG1X(const __bf16* __restrict__ Phw,
                                                const __bf16* __restrict__ QhT,
                                                __bf16* __restrict__ PRT,
                                                float* __restrict__ S1) {
    __shared__ float red[4][64][16];
    __shared__ float wt[33];
    int t = threadIdx.x;
    if (blockIdx.x < 120) {
        int ct = blockIdx.x % 15, sk = blockIdx.x / 15;
        int w = t >> 6, lane = t & 63, n = lane & 31, kb = lane >> 5;
        const __bf16* arow = Phw + (size_t)(ct * 32 + n) * NPIX;
        const __bf16* brow = QhT + (size_t)n * NPIX;
        int j0 = sk * KC + w * KW;
        f32x16 acc = {};
        #pragma unroll 6
        for (int ks = 0; ks < KW / 16; ks++) {
            int j = j0 + ks * 16 + kb * 8;
            bf16x8 a = *reinterpret_cast<const bf16x8*>(arow + j);
            bf16x8 b = *reinterpret_cast<const bf16x8*>(brow + j);
            acc = __builtin_amdgcn_mfma_f32_32x32x16_bf16(a, b, acc, 0, 0, 0);
        }
        #pragma unroll
        for (int q = 0; q < 16; q++) red[w][lane][q] = acc[q];
        __syncthreads();
        #pragma unroll
        for (int e = 0; e < 4; e++) {
            int o = t * 4 + e;
            int ln = o >> 4, q = o & 15;
            float v = red[0][ln][q] + red[1][ln][q] + red[2][ln][q] + red[3][ln][q];
            int r = (q & 3) + 8 * (q >> 2) + 4 * (ln >> 5);   // verified C/D row map
            int l = ln & 31;
            PRT[((size_t)sk * 32 + l) * NCP + ct * 32 + r] = (__bf16)v;
        }
        return;
    }
    // ---- spatX ----
    if (t < 33) { float d = (float)(t - RAD); wt[t] = fexp2((-0.5f / 9.0f) * L2E * d * d); }
    __syncthreads();
    int tid = (blockIdx.x - 120) * 256 + t;                  // NL*NPIX exact
    int l = tid / NPIX, rem = tid - l * NPIX;
    int y = rem / WW, x1 = rem - y * WW;
    const __bf16* row = QhT + (size_t)l * NPIX + y * WW;
    float acc = 0.f;
    #pragma unroll
    for (int d = 0; d < 33; d++) {
        int x2 = x1 - RAD + d;
        if ((unsigned)x2 < WW) acc = fmaf(wt[d], (float)row[x2], acc);
    }
    S1[tid] = acc;
}

// ---------- D2: GEMM2 (blocks 0..71) | spatY (blocks 72..827) ----------
// g2: Bl[l][i] = sum_sk sum_c Phi[i,c] * PRT[sk][l][c]   (deterministic, no atomics)
__global__ __launch_bounds__(256) void fusedG2Y(const __bf16* __restrict__ Phi,
                                                const __bf16* __restrict__ PRT,
                                                float* __restrict__ Bl,
                                                const float* __restrict__ S1,
                                                const float* __restrict__ norm_s,
                                                float* __restrict__ Sp) {
    __shared__ float wt[33];
    int t = threadIdx.x;
    if (blockIdx.x < 72) {
        int w = t >> 6, lane = t & 63, n = lane & 31, kb = lane >> 5;
        int it = blockIdx.x * 4 + w;                         // 288 i-tiles
        const __bf16* arow = Phi + (size_t)(it * 32 + n) * NCP;
        f32x16 acc = {};
        for (int ks = 0; ks < NCP / 16; ks++) {
            int k = ks * 16 + kb * 8;
            bf16x8 a = *reinterpret_cast<const bf16x8*>(arow + k);
            #pragma unroll
            for (int sk = 0; sk < SK; sk++) {
                bf16x8 b = *reinterpret_cast<const bf16x8*>(PRT + ((size_t)sk * 32 + n) * NCP + k);
                acc = __builtin_amdgcn_mfma_f32_32x32x16_bf16(a, b, acc, 0, 0, 0);
            }
        }
        int ibase = it * 32;
        #pragma unroll
        for (int q = 0; q < 16; q++) {
            int r = (q & 3) + 8 * (q >> 2) + 4 * kb;         // verified C/D row map
            if (n < 22) Bl[(size_t)n * NPIX + ibase + r] = acc[q];
        }
        return;
    }
    // ---- spatY ----
    if (t < 33) { float d = (float)(t - RAD); wt[t] = fexp2((-0.5f / 9.0f) * L2E * d * d); }
    __syncthreads();
    int tid = (blockIdx.x - 72) * 256 + t;
    int l = tid / NPIX, rem = tid - l * NPIX;
    int y1 = rem / WW, x = rem - y1 * WW;
    const float* col = S1 + l * NPIX + x;
    float acc = 0.f;
    #pragma unroll
    for (int d = 0; d < 33; d++) {
        int y2 = y1 - RAD + d;
        if ((unsigned)y2 < WW) acc = fmaf(wt[d], col[y2 * WW], acc);
    }
    Sp[tid] = acc * norm_s[rem];
}

// ---------- combine + bilateral norm + softmax -> QhT (144 x 64 wide grid) ----------
__global__ __launch_bounds__(64) void combZ(const float* __restrict__ Sp, const float* __restrict__ Bl,
                                            const float* __restrict__ Ms, const float* __restrict__ Mb,
                                            const float* __restrict__ unary, float* __restrict__ outp,
                                            __bf16* __restrict__ QhT, int wq) {
    __shared__ float sMs[NL * NL], sMb[NL * NL];
    int t = threadIdx.x;
    for (int k = t; k < NL * NL; k += 64) { sMs[k] = Ms[k]; sMb[k] = Mb[k]; }
    __syncthreads();
    int i = blockIdx.x * 64 + t;
    if (i >= NPIX) return;
    float inv = 1.0f / (Bl[(size_t)21 * NPIX + i] + 1e-8f);
    float sp[NL], bl[NL], v[NL];
    #pragma unroll
    for (int p = 0; p < NL; p++) { sp[p] = Sp[p * NPIX + i]; bl[p] = Bl[p * NPIX + i] * inv; }
    #pragma unroll
    for (int l = 0; l < NL; l++) {
        float a = unary[l * NPIX + i];
        #pragma unroll
        for (int p = 0; p < NL; p++) {
            a = fmaf(sMs[l * NL + p], sp[p], a);
            a = fmaf(sMb[l * NL + p], bl[p], a);
        }
        outp[l * NPIX + i] = a;
        v[l] = a;
    }
    if (!wq) return;
    float m = -1e30f;
    #pragma unroll
    for (int l = 0; l < NL; l++) m = fmaxf(m, v[l]);
    float s = 0.f;
    #pragma unroll
    for (int l = 0; l < NL; l++) { v[l] = fexp2((v[l] - m) * L2E); s += v[l]; }
    float qi = 1.0f / s;
    #pragma unroll
    for (int l = 0; l < NL; l++) QhT[(size_t)l * NPIX + i] = (__bf16)(v[l] * qi);
}

extern "C" void kernel_launch(void* const* d_in, const int* in_sizes, int n_in,
                              void* d_out, int out_size, void* d_ws, size_t ws_size,
                              hipStream_t stream) {
    const float* img   = (const float*)d_in[0];
    const float* logit = (const float*)d_in[1];
    const float* Wsm   = (const float*)d_in[2];
    const float* Wbm   = (const float*)d_in[3];
    const float* Cm    = (const float*)d_in[4];
    float* out = (float*)d_out;
    float* ws  = (float*)d_ws;

    // workspace layout (float offsets)
    float* S1     = ws;                        // [0, 193536)
    float* Sp     = ws + 193536;               // [193536, 387072)
    float* Bl     = ws + 387072;               // [387072, 589824)  22 rows
    float* norm_s = ws + 589824;               // [589824, 599040)
    float* Ms     = ws + 599040;               // [599040, 599488)
    float* Mb     = ws + 599488;               // [599488, 599936)
    __bf16* QhT   = (__bf16*)(ws + 599936);    // [599936, 747392)   32*NPIX bf16
    __bf16* Phw   = (__bf16*)(ws + 747392);    // [747392, 2959232)  NCP*NPIX bf16
    __bf16* Phi   = (__bf16*)(ws + 2959232);   // [2959232, 5171072) NPIX*NCP bf16
    __bf16* PRT   = (__bf16*)(ws + 5171072);   // [5171072, 5232512) SK*32*NCP bf16

    featK<<<36, 256, 0, stream>>>(img, Phw, Phi, norm_s, QhT);
    matK<<<1, 448, 0, stream>>>(Cm, Wsm, Wbm, Ms, Mb);
    smax0<<<36, 256, 0, stream>>>(logit, QhT);
    for (int it = 0; it < 5; ++it) {
        fusedG1X<<<876, 256, 0, stream>>>(Phw, QhT, PRT, S1);
        fusedG2Y<<<828, 256, 0, stream>>>(Phi, PRT, Bl, S1, norm_s, Sp);
        combZ<<<144, 64, 0, stream>>>(Sp, Bl, Ms, Mb, logit, out, QhT, it < 4 ? 1 : 0);
    }
}

// Round 18
// 346.522 us; speedup vs baseline: 1.1386x; 1.1386x over previous
//
#include <hip/hip_runtime.h>

#define NPIX 9216
#define NL   21
#define WW   96
#define RAD  16
#define NC   462            // monomials deg<=6 in 5 vars
#define NCP  480            // padded to 15 x 32
#define SK   8              // K-splits of GEMM1
#define KC   1152           // NPIX / SK
#define KW   288            // KC / 4 waves
#define L2E  1.44269504088896340736f

typedef __bf16 bf16x8 __attribute__((ext_vector_type(8)));
typedef float  f32x16 __attribute__((ext_vector_type(16)));

__device__ __forceinline__ float fexp2(float x) { return __builtin_amdgcn_exp2f(x); }

// ---------- one-time: monomial table (packed exponents + coefficient) ----------
__global__ __launch_bounds__(512) void tabK(float2* __restrict__ tab) {
    int t = threadIdx.x;
    if (t >= NCP) return;
    const float rf[7] = {1.f, 1.f, 0.5f, 1.f/6.f, 1.f/24.f, 1.f/120.f, 1.f/720.f};
    float coef = 0.f; int pk = 0;
    int c = 0;
    for (int a0 = 0; a0 <= 6; a0++)
    for (int a1 = 0; a1 <= 6 - a0; a1++)
    for (int a2 = 0; a2 <= 6 - a0 - a1; a2++)
    for (int a3 = 0; a3 <= 6 - a0 - a1 - a2; a3++)
    for (int a4 = 0; a4 <= 6 - a0 - a1 - a2 - a3; a4++) {
        if (c == t) {
            coef = sqrtf(rf[a0] * rf[a1] * rf[a2] * rf[a3] * rf[a4]);
            pk = a0 | (a1 << 3) | (a2 << 6) | (a3 << 9) | (a4 << 12);
        }
        c++;
    }
    if (t >= NC) { coef = 0.f; pk = 0; }     // zero padding channels
    tab[t] = make_float2(coef, __int_as_float(pk));
}

// ---------- prep: lifted Taylor features, (pixel x channel-tile) grid ----------
// Phw[c][j] = phi_c(fj) e^{-sj} (c-major); Phi[i][c] = same, row-major.
__global__ __launch_bounds__(256) void featK(const float* __restrict__ img,
                                             __bf16* __restrict__ Phw, __bf16* __restrict__ Phi,
                                             float* __restrict__ norm_s, __bf16* __restrict__ QhT,
                                             const float2* __restrict__ tab) {
    int i = blockIdx.x * 256 + threadIdx.x;
    if (i >= NPIX) return;
    int c0 = blockIdx.y * 32;
    int y = i / WW, x = i - y * WW;
    float f0 = (float)x * (1.0f / 160.0f);
    float f1 = (float)y * (1.0f / 160.0f);
    float f2 = img[0 * NPIX + i] * (1.0f / 3.0f);
    float f3 = img[1 * NPIX + i] * (1.0f / 3.0f);
    float f4 = img[2 * NPIX + i] * (1.0f / 3.0f);
    float sn = 0.5f * (f0*f0 + f1*f1 + f2*f2 + f3*f3 + f4*f4);
    float wgt = fexp2(-sn * L2E);                                // e^{-s}

    if (blockIdx.y == 0) {
        QhT[(size_t)21 * NPIX + i] = (__bf16)1.0f;
        #pragma unroll
        for (int l = 22; l < 32; l++) QhT[(size_t)l * NPIX + i] = (__bf16)0.0f;
        const float cs = (-0.5f / 9.0f) * L2E;
        float sx = 0.f, sy = 0.f;
        int xa = max(0, x - RAD), xb = min(WW - 1, x + RAD);
        int ya = max(0, y - RAD), yb = min(WW - 1, y + RAD);
        for (int t = xa; t <= xb; t++) { float dx = (float)(x - t); sx += fexp2(cs * dx * dx); }
        for (int t = ya; t <= yb; t++) { float dy = (float)(y - t); sy += fexp2(cs * dy * dy); }
        norm_s[i] = 1.0f / (sx * sy + 1e-8f);
    }

    __bf16 buf[8];
    #pragma unroll
    for (int g = 0; g < 4; g++) {
        #pragma unroll
        for (int e = 0; e < 8; e++) {
            int cc = g * 8 + e;
            float2 te = tab[c0 + cc];                 // wave-uniform -> scalar load
            int pk = __float_as_int(te.y);
            float v = te.x * wgt;
            int a0 = pk & 7, a1 = (pk >> 3) & 7, a2 = (pk >> 6) & 7,
                a3 = (pk >> 9) & 7, a4 = (pk >> 12) & 7;
            for (int k = 0; k < a0; k++) v *= f0;     // uniform bounds, no divergence
            for (int k = 0; k < a1; k++) v *= f1;
            for (int k = 0; k < a2; k++) v *= f2;
            for (int k = 0; k < a3; k++) v *= f3;
            for (int k = 0; k < a4; k++) v *= f4;
            __bf16 h = (__bf16)v;
            Phw[(size_t)(c0 + cc) * NPIX + i] = h;    // coalesced across lanes
            buf[e] = h;
        }
        *reinterpret_cast<bf16x8*>(Phi + (size_t)i * NCP + c0 + g * 8) =
            *reinterpret_cast<bf16x8*>(buf);
    }
}

// ---------- fold 21x21 matrices ----------
__global__ __launch_bounds__(448) void matK(const float* __restrict__ Cm, const float* __restrict__ Wsm,
                                            const float* __restrict__ Wbm,
                                            float* __restrict__ Ms, float* __restrict__ Mb) {
    int t = threadIdx.x;
    if (t >= NL * NL) return;
    int l = t / NL, p = t - l * NL;
    float a = 0.f, b = 0.f;
    for (int m = 0; m < NL; m++) {
        float c = Cm[l * NL + m];
        a = fmaf(c, Wsm[m * NL + p], a);
        b = fmaf(c, Wbm[m * NL + p], b);
    }
    Ms[t] = a; Mb[t] = b;
}

// ---------- iter-0 softmax -> QhT ----------
__global__ __launch_bounds__(256) void smax0(const float* __restrict__ cur, __bf16* __restrict__ QhT) {
    int i = blockIdx.x * 256 + threadIdx.x;
    if (i >= NPIX) return;
    float v[NL]; float m = -1e30f;
    #pragma unroll
    for (int l = 0; l < NL; l++) { v[l] = cur[l * NPIX + i]; m = fmaxf(m, v[l]); }
    float s = 0.f;
    #pragma unroll
    for (int l = 0; l < NL; l++) { v[l] = fexp2((v[l] - m) * L2E); s += v[l]; }
    float inv = 1.0f / s;
    #pragma unroll
    for (int l = 0; l < NL; l++) QhT[(size_t)l * NPIX + i] = (__bf16)(v[l] * inv);
}

// ---------- D1: GEMM1 partials (blocks 0..119) | spatX (blocks 120..875) ----------
// g1: PRT[sk][l][c] = sum_{j in chunk sk} Phw[c,j] * QhT[l,j]  (4-wave split-K + LDS reduce)
__global__ __launch_bounds__(256) void fusedG1X(const __bf16* __restrict__ Phw,
                                                const __bf16* __restrict__ QhT,
                                                __bf16* __restrict__ PRT,
                                                float* __restrict__ S1) {
    __shared__ float red[4][64][16];
    __shared__ float wt[33];
    int t = threadIdx.x;
    if (blockIdx.x < 120) {
        int ct = blockIdx.x % 15, sk = blockIdx.x / 15;
        int w = t >> 6, lane = t & 63, n = lane & 31, kb = lane >> 5;
        const __bf16* arow = Phw + (size_t)(ct * 32 + n) * NPIX;
        const __bf16* brow = QhT + (size_t)n * NPIX;
        int j0 = sk * KC + w * KW;
        f32x16 acc = {};
        #pragma unroll 6
        for (int ks = 0; ks < KW / 16; ks++) {
            int j = j0 + ks * 16 + kb * 8;
            bf16x8 a = *reinterpret_cast<const bf16x8*>(arow + j);
            bf16x8 b = *reinterpret_cast<const bf16x8*>(brow + j);
            acc = __builtin_amdgcn_mfma_f32_32x32x16_bf16(a, b, acc, 0, 0, 0);
        }
        #pragma unroll
        for (int q = 0; q < 16; q++) red[w][lane][q] = acc[q];
        __syncthreads();
        #pragma unroll
        for (int e = 0; e < 4; e++) {
            int o = t * 4 + e;
            int ln = o >> 4, q = o & 15;
            float v = red[0][ln][q] + red[1][ln][q] + red[2][ln][q] + red[3][ln][q];
            int r = (q & 3) + 8 * (q >> 2) + 4 * (ln >> 5);   // verified C/D row map
            int l = ln & 31;
            PRT[((size_t)sk * 32 + l) * NCP + ct * 32 + r] = (__bf16)v;
        }
        return;
    }
    // ---- spatX ----
    if (t < 33) { float d = (float)(t - RAD); wt[t] = fexp2((-0.5f / 9.0f) * L2E * d * d); }
    __syncthreads();
    int tid = (blockIdx.x - 120) * 256 + t;                  // NL*NPIX exact
    int l = tid / NPIX, rem = tid - l * NPIX;
    int y = rem / WW, x1 = rem - y * WW;
    const __bf16* row = QhT + (size_t)l * NPIX + y * WW;
    float acc = 0.f;
    #pragma unroll
    for (int d = 0; d < 33; d++) {
        int x2 = x1 - RAD + d;
        if ((unsigned)x2 < WW) acc = fmaf(wt[d], (float)row[x2], acc);
    }
    S1[tid] = acc;
}

// ---------- D2: GEMM2 (blocks 0..71) | spatY (blocks 72..827) ----------
__global__ __launch_bounds__(256) void fusedG2Y(const __bf16* __restrict__ Phi,
                                                const __bf16* __restrict__ PRT,
                                                float* __restrict__ Bl,
                                                const float* __restrict__ S1,
                                                const float* __restrict__ norm_s,
                                                float* __restrict__ Sp) {
    __shared__ float wt[33];
    int t = threadIdx.x;
    if (blockIdx.x < 72) {
        int w = t >> 6, lane = t & 63, n = lane & 31, kb = lane >> 5;
        int it = blockIdx.x * 4 + w;                         // 288 i-tiles
        const __bf16* arow = Phi + (size_t)(it * 32 + n) * NCP;
        f32x16 acc = {};
        for (int ks = 0; ks < NCP / 16; ks++) {
            int k = ks * 16 + kb * 8;
            bf16x8 a = *reinterpret_cast<const bf16x8*>(arow + k);
            #pragma unroll
            for (int sk = 0; sk < SK; sk++) {
                bf16x8 b = *reinterpret_cast<const bf16x8*>(PRT + ((size_t)sk * 32 + n) * NCP + k);
                acc = __builtin_amdgcn_mfma_f32_32x32x16_bf16(a, b, acc, 0, 0, 0);
            }
        }
        int ibase = it * 32;
        #pragma unroll
        for (int q = 0; q < 16; q++) {
            int r = (q & 3) + 8 * (q >> 2) + 4 * kb;         // verified C/D row map
            if (n < 22) Bl[(size_t)n * NPIX + ibase + r] = acc[q];
        }
        return;
    }
    // ---- spatY ----
    if (t < 33) { float d = (float)(t - RAD); wt[t] = fexp2((-0.5f / 9.0f) * L2E * d * d); }
    __syncthreads();
    int tid = (blockIdx.x - 72) * 256 + t;
    int l = tid / NPIX, rem = tid - l * NPIX;
    int y1 = rem / WW, x = rem - y1 * WW;
    const float* col = S1 + l * NPIX + x;
    float acc = 0.f;
    #pragma unroll
    for (int d = 0; d < 33; d++) {
        int y2 = y1 - RAD + d;
        if ((unsigned)y2 < WW) acc = fmaf(wt[d], col[y2 * WW], acc);
    }
    Sp[tid] = acc * norm_s[rem];
}

// ---------- combine + bilateral norm + softmax -> QhT (144 x 64 wide grid) ----------
__global__ __launch_bounds__(64) void combZ(const float* __restrict__ Sp, const float* __restrict__ Bl,
                                            const float* __restrict__ Ms, const float* __restrict__ Mb,
                                            const float* __restrict__ unary, float* __restrict__ outp,
                                            __bf16* __restrict__ QhT, int wq) {
    __shared__ float sMs[NL * NL], sMb[NL * NL];
    int t = threadIdx.x;
    for (int k = t; k < NL * NL; k += 64) { sMs[k] = Ms[k]; sMb[k] = Mb[k]; }
    __syncthreads();
    int i = blockIdx.x * 64 + t;
    if (i >= NPIX) return;
    float inv = 1.0f / (Bl[(size_t)21 * NPIX + i] + 1e-8f);
    float sp[NL], bl[NL], v[NL];
    #pragma unroll
    for (int p = 0; p < NL; p++) { sp[p] = Sp[p * NPIX + i]; bl[p] = Bl[p * NPIX + i] * inv; }
    #pragma unroll
    for (int l = 0; l < NL; l++) {
        float a = unary[l * NPIX + i];
        #pragma unroll
        for (int p = 0; p < NL; p++) {
            a = fmaf(sMs[l * NL + p], sp[p], a);
            a = fmaf(sMb[l * NL + p], bl[p], a);
        }
        outp[l * NPIX + i] = a;
        v[l] = a;
    }
    if (!wq) return;
    float m = -1e30f;
    #pragma unroll
    for (int l = 0; l < NL; l++) m = fmaxf(m, v[l]);
    float s = 0.f;
    #pragma unroll
    for (int l = 0; l < NL; l++) { v[l] = fexp2((v[l] - m) * L2E); s += v[l]; }
    float qi = 1.0f / s;
    #pragma unroll
    for (int l = 0; l < NL; l++) QhT[(size_t)l * NPIX + i] = (__bf16)(v[l] * qi);
}

extern "C" void kernel_launch(void* const* d_in, const int* in_sizes, int n_in,
                              void* d_out, int out_size, void* d_ws, size_t ws_size,
                              hipStream_t stream) {
    const float* img   = (const float*)d_in[0];
    const float* logit = (const float*)d_in[1];
    const float* Wsm   = (const float*)d_in[2];
    const float* Wbm   = (const float*)d_in[3];
    const float* Cm    = (const float*)d_in[4];
    float* out = (float*)d_out;
    float* ws  = (float*)d_ws;

    // workspace layout (float offsets)
    float* S1     = ws;                        // [0, 193536)
    float* Sp     = ws + 193536;               // [193536, 387072)
    float* Bl     = ws + 387072;               // [387072, 589824)  22 rows
    float* norm_s = ws + 589824;               // [589824, 599040)
    float* Ms     = ws + 599040;               // [599040, 599488)
    float* Mb     = ws + 599488;               // [599488, 599936)
    __bf16* QhT   = (__bf16*)(ws + 599936);    // [599936, 747392)   32*NPIX bf16
    __bf16* Phw   = (__bf16*)(ws + 747392);    // [747392, 2959232)  NCP*NPIX bf16
    __bf16* Phi   = (__bf16*)(ws + 2959232);   // [2959232, 5171072) NPIX*NCP bf16
    __bf16* PRT   = (__bf16*)(ws + 5171072);   // [5171072, 5232512) SK*32*NCP bf16
    float2* tab   = (float2*)(ws + 5232512);   // [5232512, 5233472) 480 float2

    tabK<<<1, 512, 0, stream>>>(tab);
    featK<<<dim3(36, 15), 256, 0, stream>>>(img, Phw, Phi, norm_s, QhT, tab);
    matK<<<1, 448, 0, stream>>>(Cm, Wsm, Wbm, Ms, Mb);
    smax0<<<36, 256, 0, stream>>>(logit, QhT);
    for (int it = 0; it < 5; ++it) {
        fusedG1X<<<876, 256, 0, stream>>>(Phw, QhT, PRT, S1);
        fusedG2Y<<<828, 256, 0, stream>>>(Phi, PRT, Bl, S1, norm_s, Sp);
        combZ<<<144, 64, 0, stream>>>(Sp, Bl, Ms, Mb, logit, out, QhT, it < 4 ? 1 : 0);
    }
}